// Round 3
// baseline (344.016 us; speedup 1.0000x reference)
//
#include <hip/hip_runtime.h>

#define DMODEL   2048
#define NTHREADS 256
#define ROWS_PER_BLK 4

typedef float fx4 __attribute__((ext_vector_type(4)));

// sin/cos of theta (radians) via hardware v_sin_f32/v_cos_f32.
// HW takes REVOLUTIONS; fract-reduce first (exact: sin/cos periodic in 1 rev).
// Matches the reference's 4096-entry lerp LUT to ~3e-7; threshold is 2e-2.
__device__ __forceinline__ void fast_sincos(float theta, float& s, float& c) {
    const float INV_TWO_PI = 0.15915494309189535f;
    float r  = theta * INV_TWO_PI;
    float rr = r - floorf(r);                 // [0,1) revolutions
#if __has_builtin(__builtin_amdgcn_sinf) && __has_builtin(__builtin_amdgcn_cosf)
    s = __builtin_amdgcn_sinf(rr);            // v_sin_f32: sin(rr*2pi)
    c = __builtin_amdgcn_cosf(rr);
#else
    s = __sinf(rr * 6.283185307179586f);
    c = __cosf(rr * 6.283185307179586f);
#endif
}

__device__ __forceinline__ float fast_rcp(float x) {
#if __has_builtin(__builtin_amdgcn_rcpf)
    return __builtin_amdgcn_rcpf(x);          // ~1e-7 rel err, plenty for 2e-2
#else
    return 1.0f / x;
#endif
}

template <typename T>
__device__ __forceinline__ void nt_store(T v, T* p) {
#if __has_builtin(__builtin_nontemporal_store)
    __builtin_nontemporal_store(v, p);        // write-only output: don't cache
#else
    *p = v;
#endif
}

// 4 rows per block, 1-deep cross-row prefetch pipeline.
// KEY FIX vs rounds 0-2: __syncthreads() drains vmcnt(0) (compiler-emitted),
// killing any load overlap across the reduction barrier. We use a raw
// s_barrier with ONLY lgkmcnt(0) (LDS visibility) so the next row's 8 global
// loads stay in flight across the barrier (T4: counted/partial waits, never
// full drain in the loop). asm memory clobbers pin load placement.
__global__ __launch_bounds__(NTHREADS)
void liquid_echo_kernel(const float* __restrict__ x_real,
                        const float* __restrict__ x_imag,
                        const float* __restrict__ tvec,
                        const float* __restrict__ memory_real,
                        const float* __restrict__ memory_imag,
                        const float* __restrict__ w_trigger,
                        const float* __restrict__ b_trigger,
                        const float* __restrict__ w_state,
                        const float* __restrict__ b_state,
                        const float* __restrict__ kptr,
                        float* __restrict__ out,
                        int nrows,
                        size_t imag_off)
{
    __shared__ float red[2][NTHREADS / 64];   // double-buffered: 1 barrier/row

    const int tid = threadIdx.x;
    const int c0  = tid * 4;
    const int c1  = (DMODEL / 2) + tid * 4;
    const int row0 = blockIdx.x * ROWS_PER_BLK;

    const float k_eff = fabsf(kptr[0]) + 0.1f;   // loop-invariant scalar

    // ---- Stage registers (consumed by phase 1, refilled by prefetch)
    fx4 xr0, xr1, xi0, xi1, mr0, mr1, mi0, mi1;
    float t_next;

    // ---- Prologue: prefetch row0 (the one unavoidable latency exposure)
    {
        const size_t rb = (size_t)row0 * DMODEL;
        xr0 = *(const fx4*)(x_real + rb + c0);
        xr1 = *(const fx4*)(x_real + rb + c1);
        xi0 = *(const fx4*)(x_imag + rb + c0);
        xi1 = *(const fx4*)(x_imag + rb + c1);
        mr0 = *(const fx4*)(memory_real + rb + c0);
        mr1 = *(const fx4*)(memory_real + rb + c1);
        mi0 = *(const fx4*)(memory_imag + rb + c0);
        mi1 = *(const fx4*)(memory_imag + rb + c1);
        t_next = tvec[row0];
    }

    #pragma unroll
    for (int i = 0; i < ROWS_PER_BLK; ++i) {
        const int row = row0 + i;
        if (row >= nrows) break;               // block-uniform: barrier-safe

        const size_t rb   = (size_t)row * DMODEL;
        const float t_phi = t_next * 1.6180339887498948f;   // PHI

        // ---- Phase 1: trigger via angle-sum identity; consumes stage regs
        //   trigger_real = cos(th_r+th_i), trigger_imag = sin(th_r+th_i)
        float sxy[8], smm[8];
        float partial = 0.0f;
        {
            const fx4 wt0 = *(const fx4*)(w_trigger + c0);  // L2-resident
            const fx4 wt1 = *(const fx4*)(w_trigger + c1);
            const fx4 bt0 = *(const fx4*)(b_trigger + c0);
            const fx4 bt1 = *(const fx4*)(b_trigger + c1);
            #pragma unroll
            for (int j = 0; j < 4; ++j) {
                float iw   = fast_rcp(1.0f + fabsf(wt0[j]));
                float base = bt0[j] + t_phi;
                float sx   = xr0[j] + xi0[j];
                sxy[j]     = sx;
                smm[j]     = mr0[j] + mi0[j];
                float ths  = fmaf(sx, iw, base + base);     // th_r + th_i
                float s, c;
                fast_sincos(ths, s, c);
                partial = fmaf(c, xr0[j], partial);
                partial = fmaf(s, xi0[j], partial);
            }
            #pragma unroll
            for (int j = 0; j < 4; ++j) {
                float iw   = fast_rcp(1.0f + fabsf(wt1[j]));
                float base = bt1[j] + t_phi;
                float sx   = xr1[j] + xi1[j];
                sxy[4 + j] = sx;
                smm[4 + j] = mr1[j] + mi1[j];
                float ths  = fmaf(sx, iw, base + base);
                float s, c;
                fast_sincos(ths, s, c);
                partial = fmaf(c, xr1[j], partial);
                partial = fmaf(s, xi1[j], partial);
            }
        }

        // ---- Prefetch row i+1 into the (now free) stage regs.
        //      Issued BEFORE the barrier; the raw barrier below does NOT
        //      drain vmcnt, so these stay in flight through reduce+phase2.
        if (i + 1 < ROWS_PER_BLK && row + 1 < nrows) {
            const size_t rb2 = (size_t)(row + 1) * DMODEL;
            xr0 = *(const fx4*)(x_real + rb2 + c0);
            xr1 = *(const fx4*)(x_real + rb2 + c1);
            xi0 = *(const fx4*)(x_imag + rb2 + c0);
            xi1 = *(const fx4*)(x_imag + rb2 + c1);
            mr0 = *(const fx4*)(memory_real + rb2 + c0);
            mr1 = *(const fx4*)(memory_real + rb2 + c1);
            mi0 = *(const fx4*)(memory_imag + rb2 + c0);
            mi1 = *(const fx4*)(memory_imag + rb2 + c1);
            t_next = tvec[row + 1];
        }

        // ---- Row reduction: wave shuffle -> 4 partials -> raw barrier
        #pragma unroll
        for (int off = 32; off > 0; off >>= 1)
            partial += __shfl_down(partial, off, 64);
        if ((tid & 63) == 0) red[i & 1][tid >> 6] = partial;

        // LDS-only visibility wait + raw barrier (NO vmcnt drain).
        // memory clobbers: prefetch can't sink below; red[] read can't hoist.
        asm volatile("s_waitcnt lgkmcnt(0)" ::: "memory");
        __builtin_amdgcn_s_barrier();
        asm volatile("" ::: "memory");

        float tot = red[i & 1][0] + red[i & 1][1]
                  + red[i & 1][2] + red[i & 1][3];
        float ic    = tot * (1.0f / 45.254833995939045f);   // / sqrt(2048)
        ic          = fminf(1.0f, fmaxf(-1.0f, ic));
        float x_inv = (1.0f - ic) * 0.5f;
        const float alpha = __expf(-k_eff * x_inv);
        const float oma   = 1.0f - alpha;

        float* outr = out + rb;
        float* outi = out + imag_off + rb;

        // ---- Phase 2: blend + state phase, same identity; nt stores
        {
            const fx4 ws0 = *(const fx4*)(w_state + c0);    // L2-resident
            const fx4 ws1 = *(const fx4*)(w_state + c1);
            const fx4 bs0 = *(const fx4*)(b_state + c0);
            const fx4 bs1 = *(const fx4*)(b_state + c1);
            fx4 er, ei;
            #pragma unroll
            for (int j = 0; j < 4; ++j) {
                // (br+bi) = alpha*(xr+xi) + oma*(mr+mi)
                float sb   = fmaf(alpha, sxy[j], oma * smm[j]);
                float iw   = fast_rcp(1.0f + fabsf(ws0[j]));
                float base = bs0[j] + t_phi;
                float ths  = fmaf(sb, iw, base + base);     // th_sr + th_si
                float s, c;
                fast_sincos(ths, s, c);
                er[j] = c;
                ei[j] = s;
            }
            nt_store(er, (fx4*)(outr + c0));
            nt_store(ei, (fx4*)(outi + c0));
            #pragma unroll
            for (int j = 0; j < 4; ++j) {
                float sb   = fmaf(alpha, sxy[4 + j], oma * smm[4 + j]);
                float iw   = fast_rcp(1.0f + fabsf(ws1[j]));
                float base = bs1[j] + t_phi;
                float ths  = fmaf(sb, iw, base + base);
                float s, c;
                fast_sincos(ths, s, c);
                er[j] = c;
                ei[j] = s;
            }
            nt_store(er, (fx4*)(outr + c1));
            nt_store(ei, (fx4*)(outi + c1));
        }
    }
}

extern "C" void kernel_launch(void* const* d_in, const int* in_sizes, int n_in,
                              void* d_out, int out_size, void* d_ws, size_t ws_size,
                              hipStream_t stream) {
    const float* x_real      = (const float*)d_in[0];
    const float* x_imag      = (const float*)d_in[1];
    const float* t           = (const float*)d_in[2];
    const float* memory_real = (const float*)d_in[3];
    const float* memory_imag = (const float*)d_in[4];
    const float* w_trigger   = (const float*)d_in[5];
    const float* b_trigger   = (const float*)d_in[6];
    const float* w_state     = (const float*)d_in[7];
    const float* b_state     = (const float*)d_in[8];
    const float* k           = (const float*)d_in[9];
    // d_in[10], d_in[11] = sin/cos tables — superseded by HW trig (see fast_sincos)
    float* out = (float*)d_out;

    int B = in_sizes[0] / DMODEL;
    size_t imag_off = (size_t)out_size / 2;
    int grid = (B + ROWS_PER_BLK - 1) / ROWS_PER_BLK;

    liquid_echo_kernel<<<grid, NTHREADS, 0, stream>>>(
        x_real, x_imag, t, memory_real, memory_imag,
        w_trigger, b_trigger, w_state, b_state, k,
        out, B, imag_off);
}